// Round 7
// baseline (99.130 us; speedup 1.0000x reference)
//
#include <hip/hip_runtime.h>
#include <math.h>

// QRNN: B=8, T=4096, C=256, UNITS=256, WINDOW=2
// gates = concat(x[t-1],x[t]) @ K[512,768] + bias ; z=tanh f=sig o=sig
// c_t = f*c_{t-1} + (1-f)*z_t ; h = sig(o)*c
// GEMM M=32768 K=512 N=768, fp16 MFMA single pass.
// R7: natural dispatch order (A/B L2 reuse), BK=64 (8 K-steps, barrier cost
// halved), dbuf LDS 64KB, counted vmcnt(8), setprio. Scan chunks L=32.

#define Bq 8
#define Tq 4096
#define NCq 128
#define Lq 32

typedef __attribute__((ext_vector_type(8))) _Float16 f16x8;
typedef __attribute__((ext_vector_type(4))) float f32x4;

__device__ __forceinline__ float sigmoidf_(float x) {
    return 1.f / (1.f + __expf(-x));
}
__device__ __forceinline__ float tanh_fast(float x) {
    return 1.f - 2.f / (__expf(2.f * x) + 1.f);
}
__device__ __forceinline__ unsigned short f16b(float a) {
    _Float16 h = (_Float16)a;
    return *(unsigned short*)&h;
}
__device__ __forceinline__ void gload16(const void* g, void* l) {
    __builtin_amdgcn_global_load_lds(
        (const __attribute__((address_space(1))) void*)g,
        (__attribute__((address_space(3))) void*)l, 16, 0, 0);
}

// ---------- prep 1: x -> padded fp16 (xp[b][tp][c], tp=t+1, row 0 = zeros)
__global__ __launch_bounds__(256) void split_x(
    const float* __restrict__ x, _Float16* __restrict__ xh)
{
    int idx = blockIdx.x * 256 + threadIdx.x;
    if (idx >= Bq * 4097 * 64) return;
    int b  = idx / (4097 * 64);
    int r  = idx % (4097 * 64);
    int tp = r / 64, c4 = (r % 64) << 2;
    size_t o = ((size_t)(b * 4097 + tp) << 8) + c4;
    _Float16 h4[4] = {(_Float16)0.f, (_Float16)0.f, (_Float16)0.f, (_Float16)0.f};
    if (tp > 0) {
        const float4 v = *(const float4*)&x[((size_t)(b * 4096 + tp - 1) << 8) + c4];
        h4[0] = (_Float16)v.x; h4[1] = (_Float16)v.y;
        h4[2] = (_Float16)v.z; h4[3] = (_Float16)v.w;
    }
    *(ushort4*)&xh[o] = *(ushort4*)h4;
}

// ---------- prep 2: kernel [512][768] -> transposed fp16 [768][512]
__global__ __launch_bounds__(256) void split_k(
    const float* __restrict__ kw, _Float16* __restrict__ bh)
{
    int idx = blockIdx.x * 256 + threadIdx.x;
    if (idx >= 768 * 512) return;
    int n = idx >> 9, k = idx & 511;
    bh[((size_t)n << 9) + k] = (_Float16)kw[(size_t)k * 768 + n];
}

// ---------- main GEMM: 128x128 tile, BK=64, 4 waves (2x2), 16x16x32 f16 MFMA
__global__ __launch_bounds__(256) void conv_gemm(
    const _Float16* __restrict__ xh, const _Float16* __restrict__ bth,
    const float* __restrict__ bias,
    _Float16* __restrict__ Z, _Float16* __restrict__ G, _Float16* __restrict__ SO)
{
    __shared__ __align__(16) char smem[65536];   // 2 bufs x (A 16KB + B 16KB)
    const int tid = threadIdx.x;
    const int l = tid & 63, w = tid >> 6;
    const int wr = w >> 1, wc = w & 1;
    const int bm = blockIdx.x;            // 0..255  (M tiles)
    const int by = blockIdx.y;            // 0..5    (N tiles)
    const int b  = bm >> 5;
    const int t0 = (bm & 31) << 7;
    const int n0 = by << 7;

    f32x4 acc[4][4] = {};

    // ---- staging geometry (BK=64): tile [128 rows][64 k] fp16, 128B/row.
    // chunk c = i*256+tid (i=0..3): row = i*32+(tid>>3), 16B slot = tid&7.
    // LDS linear dest; source k pre-swizzled: slotSw = slot ^ (row&7).
    const int slotSw = (tid & 7) ^ ((tid >> 3) & 7);
    // A: xh row = b*4097 + t0 + row (+1 for kk>=4); row stride 256 halves
    size_t gaBase = ((size_t)(b * 4097 + t0 + (tid >> 3)) << 8) + slotSw * 8;
    // B: bth row = n0 + row; row stride 512 halves
    size_t gbBase = ((size_t)(n0 + (tid >> 3)) << 9) + slotSw * 8;
    const int ldsD = w << 10;             // wave dest base within i-group (bytes)

    // fragment ds_read byte offsets: off = ra*128 + ((h*4+(l>>4)) ^ (ra&7))*16
    int offA[4][2], offB[4][2];
    #pragma unroll
    for (int i = 0; i < 4; ++i) {
        int ra = wr * 64 + i * 16 + (l & 15);
        int rb = wc * 64 + i * 16 + (l & 15);
        #pragma unroll
        for (int h = 0; h < 2; ++h) {
            offA[i][h] = (ra << 7) + (((h * 4 + (l >> 4)) ^ (ra & 7)) << 4);
            offB[i][h] = (rb << 7) + (((h * 4 + (l >> 4)) ^ (ra & 7)) << 4);
        }
    }

    auto stage = [&](int buf, int kk) {
        char* bA = smem + buf * 32768;
        char* bB = bA + 16384;
        const size_t kAoff = (kk < 4) ? (size_t)(kk * 64)
                                      : (size_t)(256 + (kk - 4) * 64);
        const size_t kBoff = (size_t)kk * 64;
        #pragma unroll
        for (int i = 0; i < 4; ++i) {
            gload16(xh  + gaBase + kAoff + (size_t)i * 8192,  bA + i * 4096 + ldsD);
            gload16(bth + gbBase + kBoff + (size_t)i * 16384, bB + i * 4096 + ldsD);
        }
    };

    auto compute = [&](int buf) {
        const char* bA = smem + buf * 32768;
        const char* bB = bA + 16384;
        __builtin_amdgcn_s_setprio(1);
        #pragma unroll
        for (int h = 0; h < 2; ++h) {
            f16x8 fa[4], fb[4];
            #pragma unroll
            for (int i = 0; i < 4; ++i) {
                fa[i] = *(const f16x8*)(bA + offA[i][h]);
                fb[i] = *(const f16x8*)(bB + offB[i][h]);
            }
            #pragma unroll
            for (int mi = 0; mi < 4; ++mi)
                #pragma unroll
                for (int ni = 0; ni < 4; ++ni)
                    acc[mi][ni] = __builtin_amdgcn_mfma_f32_16x16x32_f16(
                        fa[mi], fb[ni], acc[mi][ni], 0, 0, 0);
        }
        __builtin_amdgcn_s_setprio(0);
    };

    stage(0, 0);
#define QSTEP(k, V) \
    if ((k) < 7) stage(((k) + 1) & 1, (k) + 1); \
    asm volatile("s_waitcnt vmcnt(" #V ")" ::: "memory"); \
    __builtin_amdgcn_s_barrier(); \
    compute((k) & 1); \
    asm volatile("s_waitcnt lgkmcnt(0)" ::: "memory"); \
    __builtin_amdgcn_sched_barrier(0); \
    __builtin_amdgcn_s_barrier();
    QSTEP(0, 8) QSTEP(1, 8) QSTEP(2, 8) QSTEP(3, 8)
    QSTEP(4, 8) QSTEP(5, 8) QSTEP(6, 8) QSTEP(7, 0)
#undef QSTEP

    // ---- epilogue: bias + activation, LDS transpose, coalesced fp16 stores ----
    const int gsel = by >> 1;   // 0:z 1:f(store g=1-f) 2:o
    float bb[4];
    #pragma unroll
    for (int ni = 0; ni < 4; ++ni)
        bb[ni] = bias[n0 + wc * 64 + ni * 16 + (l & 15)];

    unsigned short* Hd = (unsigned short*)smem;   // 32KB 128x128 fp16 tile
    #pragma unroll
    for (int ni = 0; ni < 4; ++ni) {
        const int cl = wc * 64 + ni * 16 + (l & 15);
        #pragma unroll
        for (int mi = 0; mi < 4; ++mi)
            #pragma unroll
            for (int r = 0; r < 4; ++r) {
                const int trl = wr * 64 + mi * 16 + ((l >> 4) << 2) + r;
                float g = acc[mi][ni][r] + bb[ni];
                float a = (gsel == 0) ? tanh_fast(g)
                        : (gsel == 1) ? sigmoidf_(-g)   // g = 1 - f
                                      : sigmoidf_(g);
                int byt = (trl << 8) + ((cl << 1) ^ (((trl >> 2) & 3) << 4));
                *(unsigned short*)((char*)Hd + byt) = f16b(a);
            }
    }
    __syncthreads();
    _Float16* Gg = (gsel == 0) ? Z : (gsel == 1) ? G : SO;
    const int u0 = n0 & 255;
    const size_t gbase = ((size_t)(b * 4096 + t0) << 8) + u0;  // halves
    #pragma unroll
    for (int j = 0; j < 8; ++j) {
        int hoff = tid * 8 + j * 2048;         // halves
        int row  = hoff >> 7;
        int cby  = (hoff & 127) << 1;          // bytes within row
        int srcB = (row << 8) + (cby ^ (((row >> 2) & 3) << 4));
        int4 v = *(const int4*)((const char*)Hd + srcB);
        *(int4*)&Gg[gbase + ((size_t)row << 8) + (cby >> 1)] = v;
    }
}

// ---------- scan kernels (chunk L=32, NC=128)
__global__ __launch_bounds__(256) void chunk_reduce(
    const _Float16* __restrict__ Z, const _Float16* __restrict__ G,
    float* __restrict__ CA, float* __restrict__ CB)
{
    const int u = threadIdx.x;
    const int blk = blockIdx.x;           // 0..1023
    const int b = blk >> 7, ck = blk & 127;
    size_t base = (((size_t)b << 12) + ck * Lq) * 256 + u;
    float A = 1.f, Bv = 0.f;
    #pragma unroll 8
    for (int s = 0; s < Lq; ++s) {
        size_t idx = base + (size_t)s * 256;
        float g = (float)G[idx];
        float z = (float)Z[idx];
        Bv = fmaf(1.f - g, Bv, g * z);
        A *= (1.f - g);
    }
    size_t cidx = ((size_t)b * NCq + ck) * 256 + u;
    CA[cidx] = A;
    CB[cidx] = Bv;
}

__global__ __launch_bounds__(256) void carry_scan(
    const float* __restrict__ CA, const float* __restrict__ CB,
    float* __restrict__ CIN)
{
    const int u = threadIdx.x;
    const int b = blockIdx.x;
    float c = 0.f;
    #pragma unroll 8
    for (int k = 0; k < NCq; ++k) {
        size_t idx = ((size_t)b * NCq + k) * 256 + u;
        CIN[idx] = c;
        c = fmaf(CA[idx], c, CB[idx]);
    }
}

__global__ __launch_bounds__(256) void apply_scan(
    const _Float16* __restrict__ Z, const _Float16* __restrict__ G,
    const _Float16* __restrict__ SO, const float* __restrict__ CIN,
    float* __restrict__ out)
{
    const int u = threadIdx.x;
    const int blk = blockIdx.x;           // 0..1023
    const int b = blk >> 7, ck = blk & 127;
    float c = CIN[((size_t)b * NCq + ck) * 256 + u];
    size_t base = (((size_t)b << 12) + ck * Lq) * 256 + u;
    #pragma unroll 8
    for (int s = 0; s < Lq; ++s) {
        size_t idx = base + (size_t)s * 256;
        float g = (float)G[idx], z = (float)Z[idx];
        c = fmaf(1.f - g, c, g * z);
        out[idx] = (float)SO[idx] * c;
    }
}

extern "C" void kernel_launch(void* const* d_in, const int* in_sizes, int n_in,
                              void* d_out, int out_size, void* d_ws, size_t ws_size,
                              hipStream_t stream) {
    const float* x    = (const float*)d_in[0];
    const float* kw   = (const float*)d_in[1];
    const float* bias = (const float*)d_in[2];
    float* out = (float*)d_out;

    char* p = (char*)d_ws;
    _Float16* xh  = (_Float16*)p; p += (size_t)Bq * 4097 * 256 * 2;
    _Float16* bth = (_Float16*)p; p += (size_t)768 * 512 * 2;
    _Float16* Z   = (_Float16*)p; p += (size_t)Bq * Tq * 256 * 2;
    _Float16* G   = (_Float16*)p; p += (size_t)Bq * Tq * 256 * 2;
    _Float16* SO  = (_Float16*)p; p += (size_t)Bq * Tq * 256 * 2;
    float* CA  = (float*)p; p += (size_t)Bq * NCq * 256 * 4;
    float* CB  = (float*)p; p += (size_t)Bq * NCq * 256 * 4;
    float* CIN = (float*)p;

    split_x<<<(Bq * 4097 * 64 + 255) / 256, 256, 0, stream>>>(x, xh);
    split_k<<<(768 * 512 + 255) / 256, 256, 0, stream>>>(kw, bth);
    dim3 g1(256, 6);
    conv_gemm<<<g1, 256, 0, stream>>>(xh, bth, bias, Z, G, SO);
    chunk_reduce<<<1024, 256, 0, stream>>>(Z, G, CA, CB);
    carry_scan<<<Bq, 256, 0, stream>>>(CA, CB, CIN);
    apply_scan<<<1024, 256, 0, stream>>>(Z, G, SO, CIN, out);
}